// Round 3
// baseline (6188.176 us; speedup 1.0000x reference)
//
#include <hip/hip_runtime.h>
#include <hip/hip_bf16.h>

using bf16 = __hip_bfloat16;

namespace {
constexpr int B = 4, T = 512, V = 576, L = 256, H = 1024, NH = 16, HD = 64, I = 4096, E = 8;
constexpr int KT = 80;          // int(1.25*512 + 7) // 8 = 80
constexpr int KI = 90;          // int(1.25*576 + 7) // 8 = 90
constexpr int PBT = B * KT;     // 320
constexpr int PBI = B * KI;     // 360

constexpr size_t FQ   = (size_t)B * T * H;   // 2,097,152
constexpr size_t FIMG = (size_t)B * V * H;   // 2,359,296
constexpr size_t FQKV = FQ + (size_t)B * V * 2 * H;  // 6,815,744
constexpr size_t FHB  = (size_t)E * PBI * I;         // 11,796,480

// small-weight (fp32-converted) region offsets
constexpr size_t sSA_B_IN = 0, sSA_B_OUT = 3072, sCA_B_IN = 4096, sCA_B_OUT = 7168;
constexpr size_t sGIW = 8192, sGIB = 24576, sGTW = 24584, sGTB = 40968;
constexpr size_t sEB1 = 40976, sEB2 = 73744;
constexpr size_t sLNQG = 81936, sLNQB = 82960, sLNCG = 83984, sLNCB = 85008, sLNFG = 86032, sLNFB = 87056;
constexpr size_t SWN = 88080;

// ws layout (float offsets)
constexpr size_t oQ = 0, oXN = oQ + FQ, oAO = oXN + FQ, oIMG = oAO + FIMG;
constexpr size_t oCTXI = oIMG + FIMG, oCTXT = oCTXI + (size_t)B * H;
constexpr size_t oPRT = oCTXT + (size_t)B * H, oPRI = oPRT + (size_t)B * T * E;
constexpr size_t oSW = oPRI + (size_t)B * V * E;
constexpr size_t oINT = oSW + SWN;                      // int region (flag + pairs + counts)
constexpr size_t oBIG = oINT + 16384;                   // QKV / HB union
constexpr size_t WS_FLOATS = oBIG + (FQKV > FHB ? FQKV : FHB);
}

__device__ __forceinline__ float b2f(bf16 x) { return __bfloat162float(x); }

// adaptive element load: f32 flag chooses interpretation of raw buffer
__device__ __forceinline__ float ldany(const void* p, int f32, size_t idx) {
  return f32 ? ((const float*)p)[idx] : b2f(((const bf16*)p)[idx]);
}

__device__ __forceinline__ float gelu_f(float x) {
  float x3 = x * x * x;
  return 0.5f * x * (1.f + tanhf(0.7978845608028654f * (x + 0.044715f * x3)));
}

// ---------------- dtype probe: bf16-interpret first 64K elems of N(0,1) data ----------------
__global__ __launch_bounds__(256) void k_detect(const void* __restrict__ q, int* __restrict__ flag) {
  __shared__ int cnt;
  if (threadIdx.x == 0) cnt = 0;
  __syncthreads();
  int local = 0;
  for (int i = threadIdx.x; i < 65536; i += 256) {
    float v = b2f(((const bf16*)q)[i]);
    if (!(fabsf(v) < 1e4f)) local++;   // counts NaN too
  }
  atomicAdd(&cnt, local);
  __syncthreads();
  if (threadIdx.x == 0) *flag = (cnt > 64) ? 1 : 0;  // 1 => buffers are fp32
}

// ---------------- adaptive convert to fp32 ----------------
__global__ __launch_bounds__(256) void k_cvt2(const void* __restrict__ in, float* __restrict__ out,
                                              int n, const int* __restrict__ flag) {
  int f32 = *flag;
  int i = blockIdx.x * 256 + threadIdx.x;
  if (i < n) out[i] = ldany(in, f32, (size_t)i);
}

__global__ __launch_bounds__(256) void k_zerof(float* __restrict__ p, int n) {
  int i = blockIdx.x * 256 + threadIdx.x;
  if (i < n) p[i] = 0.f;
}
__global__ __launch_bounds__(256) void k_zeroi(int* __restrict__ p, int n) {
  int i = blockIdx.x * 256 + threadIdx.x;
  if (i < n) p[i] = 0;
}
__global__ __launch_bounds__(256) void k_diag(float* __restrict__ out, int n, float code) {
  int i = blockIdx.x * 256 + threadIdx.x;
  if (i < n) out[i] = (i == 0 ? code : 0.f);
}

// ---------------- LayerNorm over H (fp32 gamma/beta from SW) ----------------
__global__ __launch_bounds__(256) void k_ln(const float* __restrict__ X,
                                            const float* __restrict__ g, const float* __restrict__ bta,
                                            float* __restrict__ Y) {
  int row = blockIdx.x;
  const float* x = X + (size_t)row * H;
  float s = 0.f, ss = 0.f;
  for (int j = threadIdx.x; j < H; j += 256) { float v = x[j]; s += v; ss += v * v; }
#pragma unroll
  for (int off = 32; off; off >>= 1) { s += __shfl_xor(s, off); ss += __shfl_xor(ss, off); }
  __shared__ float ls[4], lss[4];
  __shared__ float mean_s, inv_s;
  int w = threadIdx.x >> 6, lane = threadIdx.x & 63;
  if (lane == 0) { ls[w] = s; lss[w] = ss; }
  __syncthreads();
  if (threadIdx.x == 0) {
    float S1 = ls[0] + ls[1] + ls[2] + ls[3];
    float S2 = lss[0] + lss[1] + lss[2] + lss[3];
    float m = S1 / (float)H;
    float var = S2 / (float)H - m * m;   // biased var (jnp.var)
    mean_s = m;
    inv_s = 1.f / sqrtf(var + 1e-5f);
  }
  __syncthreads();
  float m = mean_s, inv = inv_s;
  float* y = Y + (size_t)row * H;
  for (int j = threadIdx.x; j < H; j += 256)
    y[j] = (x[j] - m) * inv * g[j] + bta[j];
}

// ---------------- fp32 GEMM: C[M,N] (+)= A[M,K] @ W[N,K]^T + bias[N]; W dtype-adaptive ----------------
template <bool ADD>
__global__ __launch_bounds__(256) void k_gemm(const float* __restrict__ A, int lda,
                                              const void* __restrict__ W, size_t wOff, int ldw,
                                              const float* __restrict__ bias,
                                              float* __restrict__ C, int ldc,
                                              int M, int N, int K, const int* __restrict__ flag) {
  __shared__ float As[16][65];
  __shared__ float Ws[16][65];
  int f32 = *flag;
  int n0 = blockIdx.x * 64, m0 = blockIdx.y * 64;
  int tid = threadIdx.x;
  int tm = tid >> 4, tn = tid & 15;
  float acc[4][4] = {};
  for (int k0 = 0; k0 < K; k0 += 16) {
#pragma unroll
    for (int u = 0; u < 4; ++u) {
      int idx = tid + u * 256;
      int m = idx >> 4, k = idx & 15;
      int gm = m0 + m, gn = n0 + m;
      As[k][m] = (gm < M) ? A[(size_t)gm * lda + k0 + k] : 0.f;
      Ws[k][m] = (gn < N) ? ldany(W, f32, wOff + (size_t)gn * ldw + k0 + k) : 0.f;
    }
    __syncthreads();
#pragma unroll
    for (int kk = 0; kk < 16; ++kk) {
      float a[4], bb[4];
#pragma unroll
      for (int i = 0; i < 4; ++i) { a[i] = As[kk][tm * 4 + i]; bb[i] = Ws[kk][tn * 4 + i]; }
#pragma unroll
      for (int i = 0; i < 4; ++i)
#pragma unroll
        for (int j = 0; j < 4; ++j) acc[i][j] += a[i] * bb[j];
    }
    __syncthreads();
  }
#pragma unroll
  for (int i = 0; i < 4; ++i) {
    int gm = m0 + tm * 4 + i;
    if (gm >= M) continue;
#pragma unroll
    for (int j = 0; j < 4; ++j) {
      int gn = n0 + tn * 4 + j;
      if (gn >= N) continue;
      float v = acc[i][j] + bias[gn];
      size_t o = (size_t)gm * ldc + gn;
      if (ADD) v += C[o];
      C[o] = v;
    }
  }
}

// ---------------- attention: one wave per (b,h,query), 4 queries/block ----------------
__global__ __launch_bounds__(256) void k_attn(const float* __restrict__ Qb, int qStride,
                                              const float* __restrict__ Kb, int kStride,
                                              const float* __restrict__ Vb, int vStride,
                                              float* __restrict__ Ob, int Tq, int Tk) {
  int h = blockIdx.y, b = blockIdx.z;
  int w = threadIdx.x >> 6, lane = threadIdx.x & 63;
  int t = blockIdx.x * 4 + w;
  __shared__ float qs[4][64];
  __shared__ float sc[4][640];
  qs[w][lane] = Qb[((size_t)(b * Tq + t)) * qStride + h * HD + lane];
  __syncthreads();
  const float* Kbase = Kb + ((size_t)b * Tk) * kStride + h * HD;
  for (int k0 = 0; k0 < Tk; k0 += 64) {
    int key = k0 + lane;
    float s = 0.f;
    const float* kr = Kbase + (size_t)key * kStride;
#pragma unroll 16
    for (int d = 0; d < HD; ++d) s += qs[w][d] * kr[d];
    sc[w][key] = s * 0.125f;  // 1/sqrt(64); Tk is a multiple of 64 here
  }
  float m = -1e30f;
  for (int k2 = lane; k2 < Tk; k2 += 64) m = fmaxf(m, sc[w][k2]);
#pragma unroll
  for (int off = 32; off; off >>= 1) m = fmaxf(m, __shfl_xor(m, off));
  float l = 0.f;
  for (int k2 = lane; k2 < Tk; k2 += 64) {
    float e2 = __expf(sc[w][k2] - m);
    sc[w][k2] = e2;
    l += e2;
  }
#pragma unroll
  for (int off = 32; off; off >>= 1) l += __shfl_xor(l, off);
  const float* Vbase = Vb + ((size_t)b * Tk) * vStride + h * HD + lane;
  float o = 0.f;
  for (int k2 = 0; k2 < Tk; ++k2) o += sc[w][k2] * Vbase[(size_t)k2 * vStride];
  o /= l;
  Ob[((size_t)(b * Tq + t)) * H + h * HD + lane] = o;
}

// ---------------- mean over sequence ----------------
__global__ __launch_bounds__(256) void k_mean_f32(const float* __restrict__ X, float* __restrict__ out, int S) {
  int i = blockIdx.x * 256 + threadIdx.x;
  int b = i >> 10, d = i & (H - 1);
  const float* p = X + (size_t)b * S * H + d;
  float s = 0.f;
  for (int t = 0; t < S; ++t) s += p[(size_t)t * H];
  out[i] = s / (float)S;
}
__global__ __launch_bounds__(256) void k_mean_in(const void* __restrict__ X, float* __restrict__ out,
                                                 int S, const int* __restrict__ flag) {
  int f32 = *flag;
  int i = blockIdx.x * 256 + threadIdx.x;
  int b = i >> 10, d = i & (H - 1);
  size_t base = (size_t)b * S * H + d;
  float s = 0.f;
  for (int t = 0; t < S; ++t) s += ldany(X, f32, base + (size_t)t * H);
  out[i] = s / (float)S;
}

// ---------------- gate: softmax(concat(x,ctx) @ Wg^T + bg) over E ----------------
__global__ __launch_bounds__(256) void k_gate(const float* __restrict__ X, const float* __restrict__ ctx,
                                              const float* __restrict__ Wg, const float* __restrict__ bg,
                                              float* __restrict__ probs, int S) {
  int row = blockIdx.x;
  int b = row / S;
  const float* xr = X + (size_t)row * H;
  const float* cx = ctx + (size_t)b * H;
  float p[E] = {};
  for (int j = threadIdx.x; j < 2 * H; j += 256) {
    float xv = (j < H) ? xr[j] : cx[j - H];
#pragma unroll
    for (int e = 0; e < E; ++e) p[e] += xv * Wg[(size_t)e * 2 * H + j];
  }
#pragma unroll
  for (int e = 0; e < E; ++e)
#pragma unroll
    for (int off = 32; off; off >>= 1) p[e] += __shfl_xor(p[e], off);
  __shared__ float gl[4][E];
  int w = threadIdx.x >> 6, lane = threadIdx.x & 63;
  if (lane == 0)
#pragma unroll
    for (int e = 0; e < E; ++e) gl[w][e] = p[e];
  __syncthreads();
  if (threadIdx.x == 0) {
    float lg[E], mx = -1e30f;
    for (int e = 0; e < E; ++e) {
      lg[e] = gl[0][e] + gl[1][e] + gl[2][e] + gl[3][e] + bg[e];
      mx = fmaxf(mx, lg[e]);
    }
    float ssum = 0.f;
    for (int e = 0; e < E; ++e) { lg[e] = __expf(lg[e] - mx); ssum += lg[e]; }
    float inv = 1.f / ssum;
    for (int e = 0; e < E; ++e) probs[(size_t)row * E + e] = lg[e] * inv;
  }
}

// ---------------- expert-choice top-k (NaN-safe, clamped) ----------------
__global__ __launch_bounds__(256) void k_topk(const float* __restrict__ probs, int S, int k,
                                              int* __restrict__ pairs, int* __restrict__ counts, int PB) {
  int e = blockIdx.x, b = blockIdx.y;
  __shared__ float vals[640];
  __shared__ float bv[256];
  __shared__ int bi[256];
  int tid = threadIdx.x;
  for (int j = tid; j < S; j += 256) {
    float v = probs[((size_t)b * S + j) * E + e];
    vals[j] = (v == v) ? v : -1e30f;   // sanitize NaN
  }
  __syncthreads();
  for (int it = 0; it < k; ++it) {
    float best = -2e30f; int besti = 0;
    for (int j = tid; j < S; j += 256) {
      float v = vals[j];
      if (v > best || (v == best && j < besti)) { best = v; besti = j; }
    }
    bv[tid] = best; bi[tid] = besti;
    __syncthreads();
    for (int st = 128; st; st >>= 1) {
      if (tid < st) {
        if (bv[tid + st] > bv[tid] || (bv[tid + st] == bv[tid] && bi[tid + st] < bi[tid])) {
          bv[tid] = bv[tid + st]; bi[tid] = bi[tid + st];
        }
      }
      __syncthreads();
    }
    if (tid == 0) {
      int sidx = bi[0];
      if ((unsigned)sidx >= (unsigned)S) sidx = 0;  // clamp: never fault
      pairs[e * PB + b * k + it] = b * S + sidx;
      atomicAdd(&counts[b * S + sidx], 1);
      vals[sidx] = -1e30f;
    }
    __syncthreads();
  }
}

// ---------------- MoE up-proj (indirect rows, gelu) ----------------
__global__ __launch_bounds__(256) void k_moe_up(const float* __restrict__ X, int nTok,
                                                const int* __restrict__ pairs, int PB,
                                                const void* __restrict__ W1, const float* __restrict__ B1,
                                                float* __restrict__ Hb, const int* __restrict__ flag) {
  int e = blockIdx.z;
  int n0 = blockIdx.x * 64, m0 = blockIdx.y * 64;
  __shared__ float As[16][65];
  __shared__ float Ws[16][65];
  __shared__ int rowIdx[64];
  int f32 = *flag;
  int tid = threadIdx.x;
  if (tid < 64) {
    int r = m0 + tid;
    int ri = (r < PB) ? pairs[e * PB + r] : -1;
    if ((unsigned)ri >= (unsigned)nTok) ri = -1;   // clamp
    rowIdx[tid] = ri;
  }
  __syncthreads();
  int tm = tid >> 4, tn = tid & 15;
  float acc[4][4] = {};
  for (int k0 = 0; k0 < H; k0 += 16) {
#pragma unroll
    for (int u = 0; u < 4; ++u) {
      int idx = tid + u * 256;
      int m = idx >> 4, k = idx & 15;
      int ri = rowIdx[m];
      As[k][m] = (ri >= 0) ? X[(size_t)ri * H + k0 + k] : 0.f;
      Ws[k][m] = ldany(W1, f32, (size_t)e * I * H + (size_t)(n0 + m) * H + k0 + k);
    }
    __syncthreads();
#pragma unroll
    for (int kk = 0; kk < 16; ++kk) {
      float a[4], bb[4];
#pragma unroll
      for (int i = 0; i < 4; ++i) { a[i] = As[kk][tm * 4 + i]; bb[i] = Ws[kk][tn * 4 + i]; }
#pragma unroll
      for (int i = 0; i < 4; ++i)
#pragma unroll
        for (int j = 0; j < 4; ++j) acc[i][j] += a[i] * bb[j];
    }
    __syncthreads();
  }
  const float* bb1 = B1 + (size_t)e * I;
#pragma unroll
  for (int i = 0; i < 4; ++i) {
    int r = m0 + tm * 4 + i;
    if (r >= PB) continue;
#pragma unroll
    for (int j = 0; j < 4; ++j) {
      int gn = n0 + tn * 4 + j;
      float v = acc[i][j] + bb1[gn];
      Hb[((size_t)e * PB + r) * I + gn] = gelu_f(v);
    }
  }
}

// ---------------- MoE down-proj + bias + scatter-add ----------------
__global__ __launch_bounds__(256) void k_moe_down(const float* __restrict__ Hb, int nTok,
                                                  const int* __restrict__ pairs, int PB,
                                                  const void* __restrict__ W2, const float* __restrict__ B2,
                                                  float* __restrict__ ACC, const int* __restrict__ flag) {
  int e = blockIdx.z;
  int n0 = blockIdx.x * 64, m0 = blockIdx.y * 64;
  __shared__ float As[16][65];
  __shared__ float Ws[16][65];
  int f32 = *flag;
  int tid = threadIdx.x;
  const float* A = Hb + (size_t)e * PB * I;
  int tm = tid >> 4, tn = tid & 15;
  float acc[4][4] = {};
  for (int k0 = 0; k0 < I; k0 += 16) {
#pragma unroll
    for (int u = 0; u < 4; ++u) {
      int idx = tid + u * 256;
      int m = idx >> 4, k = idx & 15;
      int gm = m0 + m;
      As[k][m] = (gm < PB) ? A[(size_t)gm * I + k0 + k] : 0.f;
      Ws[k][m] = ldany(W2, f32, (size_t)e * H * I + (size_t)(n0 + m) * I + k0 + k);
    }
    __syncthreads();
#pragma unroll
    for (int kk = 0; kk < 16; ++kk) {
      float a[4], bb[4];
#pragma unroll
      for (int i = 0; i < 4; ++i) { a[i] = As[kk][tm * 4 + i]; bb[i] = Ws[kk][tn * 4 + i]; }
#pragma unroll
      for (int i = 0; i < 4; ++i)
#pragma unroll
        for (int j = 0; j < 4; ++j) acc[i][j] += a[i] * bb[j];
    }
    __syncthreads();
  }
  const float* bb2 = B2 + (size_t)e * H;
#pragma unroll
  for (int i = 0; i < 4; ++i) {
    int r = m0 + tm * 4 + i;
    if (r >= PB) continue;
    int tok = pairs[e * PB + r];
    if ((unsigned)tok >= (unsigned)nTok) tok = 0;  // clamp: never fault
#pragma unroll
    for (int j = 0; j < 4; ++j) {
      int gn = n0 + tn * 4 + j;
      float v = acc[i][j] + bb2[gn];
      atomicAdd(&ACC[(size_t)tok * H + gn], v);
    }
  }
}

// ---------------- final: out = fp32(base + acc/max(count,1)) ----------------
__global__ __launch_bounds__(256) void k_final(const float* __restrict__ base, const float* __restrict__ acc,
                                               const int* __restrict__ cnt, float* __restrict__ out, int n) {
  int i = blockIdx.x * 256 + threadIdx.x;
  if (i >= n) return;
  int row = i >> 10;
  int c = cnt[row]; if (c < 1) c = 1;
  out[i] = base[i] + acc[i] / (float)c;
}

extern "C" void kernel_launch(void* const* d_in, const int* in_sizes, int n_in,
                              void* d_out, int out_size, void* d_ws, size_t ws_size,
                              hipStream_t stream) {
  float* out = (float*)d_out;    // reference output dtype is float32
  dim3 blk(256);
  const int OUT_N = (int)(FQ + FIMG);
  int outN = out_size;  // actual, for diag fills

  // ---- validate shapes ----
  static const int EXP[25] = {
    B * T * H, B * V * H, B * L * H,
    3 * H * H, 3 * H, H * H, H,
    3 * H * H, 3 * H, H * H, H,
    E * 2 * H, E, E * 2 * H, E,
    E * I * H, E * I, E * H * I, E * H,
    H, H, H, H, H, H
  };
  if (n_in != 25) { k_diag<<<dim3((outN + 255) / 256), blk, 0, stream>>>(out, outN, 40000.f); return; }
  for (int i = 0; i < 25; ++i)
    if (in_sizes[i] != EXP[i]) {
      k_diag<<<dim3((outN + 255) / 256), blk, 0, stream>>>(out, outN, 20000.f + 1000.f * i);
      return;
    }
  if (out_size != OUT_N) { k_diag<<<dim3((outN + 255) / 256), blk, 0, stream>>>(out, outN, 30000.f); return; }
  if (ws_size < WS_FLOATS * sizeof(float)) {
    k_diag<<<dim3((outN + 255) / 256), blk, 0, stream>>>(out, outN, 12345.f);
    return;
  }

  float* wsf = (float*)d_ws;
  float* Q = wsf + oQ;  float* XN = wsf + oXN;  float* AO = wsf + oAO;  float* IMG32 = wsf + oIMG;
  float* CTXI = wsf + oCTXI;  float* CTXT = wsf + oCTXT;
  float* PRT = wsf + oPRT;    float* PRI = wsf + oPRI;
  float* SW = wsf + oSW;
  int* FLAG = (int*)(wsf + oINT);
  int* PAIRS_T = FLAG + 1;
  int* PAIRS_I = PAIRS_T + E * PBT;
  int* CNT_T = PAIRS_I + E * PBI;
  int* CNT_I = CNT_T + B * T;
  float* QKV = wsf + oBIG;   // attention phase
  float* HB = wsf + oBIG;    // MoE phase (QKV dead by then)

  // ---- dtype probe (defensive; expected fp32) ----
  k_detect<<<dim3(1), blk, 0, stream>>>(d_in[0], FLAG);

  // ---- convert small params to fp32 ----
  struct CV { int idx; size_t off; int n; };
  const CV cvs[16] = {
    {4, sSA_B_IN, 3 * H}, {6, sSA_B_OUT, H}, {8, sCA_B_IN, 3 * H}, {10, sCA_B_OUT, H},
    {11, sGIW, E * 2 * H}, {12, sGIB, E}, {13, sGTW, E * 2 * H}, {14, sGTB, E},
    {16, sEB1, E * I}, {18, sEB2, E * H},
    {19, sLNQG, H}, {20, sLNQB, H}, {21, sLNCG, H}, {22, sLNCB, H}, {23, sLNFG, H}, {24, sLNFB, H}
  };
  for (int c = 0; c < 16; ++c)
    k_cvt2<<<dim3((cvs[c].n + 255) / 256), blk, 0, stream>>>(d_in[cvs[c].idx], SW + cvs[c].off, cvs[c].n, FLAG);

  // ---- activations to fp32 working copies ----
  k_cvt2<<<dim3((int)(FQ / 256)), blk, 0, stream>>>(d_in[0], Q, (int)FQ, FLAG);
  k_cvt2<<<dim3((int)(FIMG / 256)), blk, 0, stream>>>(d_in[1], IMG32, (int)FIMG, FLAG);

  // ---- 1) self-attention ----
  k_ln<<<dim3(B * T), blk, 0, stream>>>(Q, SW + sLNQG, SW + sLNQB, XN);
  k_gemm<false><<<dim3(3 * H / 64, B * T / 64), blk, 0, stream>>>(
      XN, H, d_in[3], 0, H, SW + sSA_B_IN, QKV, 3 * H, B * T, 3 * H, H, FLAG);
  k_attn<<<dim3(T / 4, NH, B), blk, 0, stream>>>(QKV, 3 * H, QKV + H, 3 * H, QKV + 2 * H, 3 * H, AO, T, T);
  k_gemm<true><<<dim3(H / 64, B * T / 64), blk, 0, stream>>>(
      AO, H, d_in[5], 0, H, SW + sSA_B_OUT, Q, H, B * T, H, H, FLAG);

  // ---- 2) cross-attention ----
  k_ln<<<dim3(B * T), blk, 0, stream>>>(Q, SW + sLNCG, SW + sLNCB, XN);
  k_gemm<false><<<dim3(H / 64, B * T / 64), blk, 0, stream>>>(
      XN, H, d_in[7], 0, H, SW + sCA_B_IN, QKV, H, B * T, H, H, FLAG);
  k_gemm<false><<<dim3(2 * H / 64, B * V / 64), blk, 0, stream>>>(
      IMG32, H, d_in[7], (size_t)H * H, H, SW + sCA_B_IN + H, QKV + FQ, 2 * H, B * V, 2 * H, H, FLAG);
  k_attn<<<dim3(T / 4, NH, B), blk, 0, stream>>>(QKV, H, QKV + FQ, 2 * H, QKV + FQ + H, 2 * H, AO, T, V);
  k_gemm<true><<<dim3(H / 64, B * T / 64), blk, 0, stream>>>(
      AO, H, d_in[9], 0, H, SW + sCA_B_OUT, Q, H, B * T, H, H, FLAG);

  // ---- 3) gating ----
  k_mean_f32<<<dim3((B * H) / 256), blk, 0, stream>>>(IMG32, CTXI, V);
  k_mean_in<<<dim3((B * H) / 256), blk, 0, stream>>>(d_in[2], CTXT, L, FLAG);
  k_gate<<<dim3(B * T), blk, 0, stream>>>(Q, CTXI, SW + sGTW, SW + sGTB, PRT, T);
  k_gate<<<dim3(B * V), blk, 0, stream>>>(IMG32, CTXT, SW + sGIW, SW + sGIB, PRI, V);
  k_zeroi<<<dim3((B * T + B * V + 255) / 256), blk, 0, stream>>>(CNT_T, B * T + B * V);

  // ---- 4) text MoE ----
  k_topk<<<dim3(E, B), blk, 0, stream>>>(PRT, T, KT, PAIRS_T, CNT_T, PBT);
  k_ln<<<dim3(B * T), blk, 0, stream>>>(Q, SW + sLNFG, SW + sLNFB, XN);
  k_zerof<<<dim3((int)(FQ / 256)), blk, 0, stream>>>(AO, (int)FQ);
  k_moe_up<<<dim3(I / 64, PBT / 64, E), blk, 0, stream>>>(XN, B * T, PAIRS_T, PBT, d_in[15], SW + sEB1, HB, FLAG);
  k_moe_down<<<dim3(H / 64, PBT / 64, E), blk, 0, stream>>>(HB, B * T, PAIRS_T, PBT, d_in[17], SW + sEB2, AO, FLAG);
  k_final<<<dim3((int)(FQ / 256)), blk, 0, stream>>>(Q, AO, CNT_T, out, (int)FQ);

  // ---- 5) image MoE ----
  k_topk<<<dim3(E, B), blk, 0, stream>>>(PRI, V, KI, PAIRS_I, CNT_I, PBI);
  k_zerof<<<dim3((int)(FIMG / 256)), blk, 0, stream>>>(AO, (int)FIMG);
  k_moe_up<<<dim3(I / 64, (PBI + 63) / 64, E), blk, 0, stream>>>(IMG32, B * V, PAIRS_I, PBI, d_in[15], SW + sEB1, HB, FLAG);
  k_moe_down<<<dim3(H / 64, (PBI + 63) / 64, E), blk, 0, stream>>>(HB, B * V, PAIRS_I, PBI, d_in[17], SW + sEB2, AO, FLAG);
  k_final<<<dim3((int)(FIMG / 256)), blk, 0, stream>>>(IMG32, AO, CNT_I, out + FQ, (int)FIMG);
}

// Round 4
// 3739.009 us; speedup vs baseline: 1.6550x; 1.6550x over previous
//
#include <hip/hip_runtime.h>
#include <hip/hip_bf16.h>

using bf16 = __hip_bfloat16;

namespace {
constexpr int B = 4, T = 512, V = 576, L = 256, H = 1024, NH = 16, HD = 64, I = 4096, E = 8;
constexpr int KT = 80;          // int(1.25*512 + 7) // 8 = 80
constexpr int KI = 90;          // int(1.25*576 + 7) // 8 = 90
constexpr int PBT = B * KT;     // 320
constexpr int PBI = B * KI;     // 360

constexpr size_t FQ   = (size_t)B * T * H;   // 2,097,152
constexpr size_t FIMG = (size_t)B * V * H;   // 2,359,296
constexpr size_t FQKV = FQ + (size_t)B * V * 2 * H;  // 6,815,744
constexpr size_t FHB  = (size_t)E * PBI * I;         // 11,796,480 (bf16 elems in MoE phase)

// small-weight (fp32-converted) region offsets
constexpr size_t sSA_B_IN = 0, sSA_B_OUT = 3072, sCA_B_IN = 4096, sCA_B_OUT = 7168;
constexpr size_t sGIW = 8192, sGIB = 24576, sGTW = 24584, sGTB = 40968;
constexpr size_t sEB1 = 40976, sEB2 = 73744;
constexpr size_t sLNQG = 81936, sLNQB = 82960, sLNCG = 83984, sLNCB = 85008, sLNFG = 86032, sLNFB = 87056;
constexpr size_t SWN = 88080;

// ws layout (float offsets)
constexpr size_t oQ = 0, oXN = oQ + FQ, oAO = oXN + FQ, oIMG = oAO + FIMG;
constexpr size_t oCTXI = oIMG + FIMG, oCTXT = oCTXI + (size_t)B * H;
constexpr size_t oPRT = oCTXT + (size_t)B * H, oPRI = oPRT + (size_t)B * T * E;
constexpr size_t oSW = oPRI + (size_t)B * V * E;
constexpr size_t oINT = oSW + SWN;                      // int region (flag + pairs + counts)
constexpr size_t oBIG = oINT + 16384;                   // QKV(f32) / HB(bf16) union
constexpr size_t WS_FLOATS = oBIG + (FQKV > FHB ? FQKV : FHB);
}

typedef __attribute__((ext_vector_type(8))) short bf16x8;
typedef __attribute__((ext_vector_type(4))) float f32x4;
typedef __attribute__((ext_vector_type(4))) int i32x4;

__device__ __forceinline__ float b2f(bf16 x) { return __bfloat162float(x); }

__device__ __forceinline__ float ldany(const void* p, int f32, size_t idx) {
  return f32 ? ((const float*)p)[idx] : b2f(((const bf16*)p)[idx]);
}

__device__ __forceinline__ unsigned int f2bf_u(float v) {   // RNE fp32->bf16 bits
  unsigned int u = __float_as_uint(v);
  u += 0x7FFFu + ((u >> 16) & 1u);
  return u >> 16;
}
__device__ __forceinline__ int pack2(float a, float b) {
  return (int)(f2bf_u(a) | (f2bf_u(b) << 16));
}

__device__ __forceinline__ float gelu_f(float x) {
  float x3 = x * x * x;
  return 0.5f * x * (1.f + tanhf(0.7978845608028654f * (x + 0.044715f * x3)));
}

// ---------------- dtype probe ----------------
__global__ __launch_bounds__(256) void k_detect(const void* __restrict__ q, int* __restrict__ flag) {
  __shared__ int cnt;
  if (threadIdx.x == 0) cnt = 0;
  __syncthreads();
  int local = 0;
  for (int i = threadIdx.x; i < 65536; i += 256) {
    float v = b2f(((const bf16*)q)[i]);
    if (!(fabsf(v) < 1e4f)) local++;
  }
  atomicAdd(&cnt, local);
  __syncthreads();
  if (threadIdx.x == 0) *flag = (cnt > 64) ? 1 : 0;
}

__global__ __launch_bounds__(256) void k_cvt2(const void* __restrict__ in, float* __restrict__ out,
                                              int n, const int* __restrict__ flag) {
  int f32 = *flag;
  int i = blockIdx.x * 256 + threadIdx.x;
  if (i < n) out[i] = ldany(in, f32, (size_t)i);
}

__global__ __launch_bounds__(256) void k_zerof(float* __restrict__ p, int n) {
  int i = blockIdx.x * 256 + threadIdx.x;
  if (i < n) p[i] = 0.f;
}
__global__ __launch_bounds__(256) void k_zeroi(int* __restrict__ p, int n) {
  int i = blockIdx.x * 256 + threadIdx.x;
  if (i < n) p[i] = 0;
}
__global__ __launch_bounds__(256) void k_diag(float* __restrict__ out, int n, float code) {
  int i = blockIdx.x * 256 + threadIdx.x;
  if (i < n) out[i] = (i == 0 ? code : 0.f);
}

// ---------------- LayerNorm ----------------
__global__ __launch_bounds__(256) void k_ln(const float* __restrict__ X,
                                            const float* __restrict__ g, const float* __restrict__ bta,
                                            float* __restrict__ Y) {
  int row = blockIdx.x;
  const float* x = X + (size_t)row * H;
  float s = 0.f, ss = 0.f;
  for (int j = threadIdx.x; j < H; j += 256) { float v = x[j]; s += v; ss += v * v; }
#pragma unroll
  for (int off = 32; off; off >>= 1) { s += __shfl_xor(s, off); ss += __shfl_xor(ss, off); }
  __shared__ float ls[4], lss[4];
  __shared__ float mean_s, inv_s;
  int w = threadIdx.x >> 6, lane = threadIdx.x & 63;
  if (lane == 0) { ls[w] = s; lss[w] = ss; }
  __syncthreads();
  if (threadIdx.x == 0) {
    float S1 = ls[0] + ls[1] + ls[2] + ls[3];
    float S2 = lss[0] + lss[1] + lss[2] + lss[3];
    float m = S1 / (float)H;
    float var = S2 / (float)H - m * m;
    mean_s = m;
    inv_s = 1.f / sqrtf(var + 1e-5f);
  }
  __syncthreads();
  float m = mean_s, inv = inv_s;
  float* y = Y + (size_t)row * H;
  for (int j = threadIdx.x; j < H; j += 256)
    y[j] = (x[j] - m) * inv * g[j] + bta[j];
}

// ---------------- fp32 GEMM (attention path; precision-critical) ----------------
template <bool ADD>
__global__ __launch_bounds__(256) void k_gemm(const float* __restrict__ A, int lda,
                                              const void* __restrict__ W, size_t wOff, int ldw,
                                              const float* __restrict__ bias,
                                              float* __restrict__ C, int ldc,
                                              int M, int N, int K, const int* __restrict__ flag) {
  __shared__ float As[16][65];
  __shared__ float Ws[16][65];
  int f32 = *flag;
  int n0 = blockIdx.x * 64, m0 = blockIdx.y * 64;
  int tid = threadIdx.x;
  int tm = tid >> 4, tn = tid & 15;
  float acc[4][4] = {};
  for (int k0 = 0; k0 < K; k0 += 16) {
#pragma unroll
    for (int u = 0; u < 4; ++u) {
      int idx = tid + u * 256;
      int m = idx >> 4, k = idx & 15;
      int gm = m0 + m, gn = n0 + m;
      As[k][m] = (gm < M) ? A[(size_t)gm * lda + k0 + k] : 0.f;
      Ws[k][m] = (gn < N) ? ldany(W, f32, wOff + (size_t)gn * ldw + k0 + k) : 0.f;
    }
    __syncthreads();
#pragma unroll
    for (int kk = 0; kk < 16; ++kk) {
      float a[4], bb[4];
#pragma unroll
      for (int i = 0; i < 4; ++i) { a[i] = As[kk][tm * 4 + i]; bb[i] = Ws[kk][tn * 4 + i]; }
#pragma unroll
      for (int i = 0; i < 4; ++i)
#pragma unroll
        for (int j = 0; j < 4; ++j) acc[i][j] += a[i] * bb[j];
    }
    __syncthreads();
  }
#pragma unroll
  for (int i = 0; i < 4; ++i) {
    int gm = m0 + tm * 4 + i;
    if (gm >= M) continue;
#pragma unroll
    for (int j = 0; j < 4; ++j) {
      int gn = n0 + tn * 4 + j;
      if (gn >= N) continue;
      float v = acc[i][j] + bias[gn];
      size_t o = (size_t)gm * ldc + gn;
      if (ADD) v += C[o];
      C[o] = v;
    }
  }
}

// ---------------- attention ----------------
__global__ __launch_bounds__(256) void k_attn(const float* __restrict__ Qb, int qStride,
                                              const float* __restrict__ Kb, int kStride,
                                              const float* __restrict__ Vb, int vStride,
                                              float* __restrict__ Ob, int Tq, int Tk) {
  int h = blockIdx.y, b = blockIdx.z;
  int w = threadIdx.x >> 6, lane = threadIdx.x & 63;
  int t = blockIdx.x * 4 + w;
  __shared__ float qs[4][64];
  __shared__ float sc[4][640];
  qs[w][lane] = Qb[((size_t)(b * Tq + t)) * qStride + h * HD + lane];
  __syncthreads();
  const float* Kbase = Kb + ((size_t)b * Tk) * kStride + h * HD;
  for (int k0 = 0; k0 < Tk; k0 += 64) {
    int key = k0 + lane;
    float s = 0.f;
    const float* kr = Kbase + (size_t)key * kStride;
#pragma unroll 16
    for (int d = 0; d < HD; ++d) s += qs[w][d] * kr[d];
    sc[w][key] = s * 0.125f;
  }
  float m = -1e30f;
  for (int k2 = lane; k2 < Tk; k2 += 64) m = fmaxf(m, sc[w][k2]);
#pragma unroll
  for (int off = 32; off; off >>= 1) m = fmaxf(m, __shfl_xor(m, off));
  float l = 0.f;
  for (int k2 = lane; k2 < Tk; k2 += 64) {
    float e2 = __expf(sc[w][k2] - m);
    sc[w][k2] = e2;
    l += e2;
  }
#pragma unroll
  for (int off = 32; off; off >>= 1) l += __shfl_xor(l, off);
  const float* Vbase = Vb + ((size_t)b * Tk) * vStride + h * HD + lane;
  float o = 0.f;
  for (int k2 = 0; k2 < Tk; ++k2) o += sc[w][k2] * Vbase[(size_t)k2 * vStride];
  o /= l;
  Ob[((size_t)(b * Tq + t)) * H + h * HD + lane] = o;
}

// ---------------- means ----------------
__global__ __launch_bounds__(256) void k_mean_f32(const float* __restrict__ X, float* __restrict__ out, int S) {
  int i = blockIdx.x * 256 + threadIdx.x;
  int b = i >> 10, d = i & (H - 1);
  const float* p = X + (size_t)b * S * H + d;
  float s = 0.f;
  for (int t = 0; t < S; ++t) s += p[(size_t)t * H];
  out[i] = s / (float)S;
}
__global__ __launch_bounds__(256) void k_mean_in(const void* __restrict__ X, float* __restrict__ out,
                                                 int S, const int* __restrict__ flag) {
  int f32 = *flag;
  int i = blockIdx.x * 256 + threadIdx.x;
  int b = i >> 10, d = i & (H - 1);
  size_t base = (size_t)b * S * H + d;
  float s = 0.f;
  for (int t = 0; t < S; ++t) s += ldany(X, f32, base + (size_t)t * H);
  out[i] = s / (float)S;
}

// ---------------- gate ----------------
__global__ __launch_bounds__(256) void k_gate(const float* __restrict__ X, const float* __restrict__ ctx,
                                              const float* __restrict__ Wg, const float* __restrict__ bg,
                                              float* __restrict__ probs, int S) {
  int row = blockIdx.x;
  int b = row / S;
  const float* xr = X + (size_t)row * H;
  const float* cx = ctx + (size_t)b * H;
  float p[E] = {};
  for (int j = threadIdx.x; j < 2 * H; j += 256) {
    float xv = (j < H) ? xr[j] : cx[j - H];
#pragma unroll
    for (int e = 0; e < E; ++e) p[e] += xv * Wg[(size_t)e * 2 * H + j];
  }
#pragma unroll
  for (int e = 0; e < E; ++e)
#pragma unroll
    for (int off = 32; off; off >>= 1) p[e] += __shfl_xor(p[e], off);
  __shared__ float gl[4][E];
  int w = threadIdx.x >> 6, lane = threadIdx.x & 63;
  if (lane == 0)
#pragma unroll
    for (int e = 0; e < E; ++e) gl[w][e] = p[e];
  __syncthreads();
  if (threadIdx.x == 0) {
    float lg[E], mx = -1e30f;
    for (int e = 0; e < E; ++e) {
      lg[e] = gl[0][e] + gl[1][e] + gl[2][e] + gl[3][e] + bg[e];
      mx = fmaxf(mx, lg[e]);
    }
    float ssum = 0.f;
    for (int e = 0; e < E; ++e) { lg[e] = __expf(lg[e] - mx); ssum += lg[e]; }
    float inv = 1.f / ssum;
    for (int e = 0; e < E; ++e) probs[(size_t)row * E + e] = lg[e] * inv;
  }
}

// ---------------- top-k (NaN-safe, clamped) ----------------
__global__ __launch_bounds__(256) void k_topk(const float* __restrict__ probs, int S, int k,
                                              int* __restrict__ pairs, int* __restrict__ counts, int PB) {
  int e = blockIdx.x, b = blockIdx.y;
  __shared__ float vals[640];
  __shared__ float bv[256];
  __shared__ int bi[256];
  int tid = threadIdx.x;
  for (int j = tid; j < S; j += 256) {
    float v = probs[((size_t)b * S + j) * E + e];
    vals[j] = (v == v) ? v : -1e30f;
  }
  __syncthreads();
  for (int it = 0; it < k; ++it) {
    float best = -2e30f; int besti = 0;
    for (int j = tid; j < S; j += 256) {
      float v = vals[j];
      if (v > best || (v == best && j < besti)) { best = v; besti = j; }
    }
    bv[tid] = best; bi[tid] = besti;
    __syncthreads();
    for (int st = 128; st; st >>= 1) {
      if (tid < st) {
        if (bv[tid + st] > bv[tid] || (bv[tid + st] == bv[tid] && bi[tid + st] < bi[tid])) {
          bv[tid] = bv[tid + st]; bi[tid] = bi[tid + st];
        }
      }
      __syncthreads();
    }
    if (tid == 0) {
      int sidx = bi[0];
      if ((unsigned)sidx >= (unsigned)S) sidx = 0;
      pairs[e * PB + b * k + it] = b * S + sidx;
      atomicAdd(&counts[b * S + sidx], 1);
      vals[sidx] = -1e30f;
    }
    __syncthreads();
  }
}

// ================= MFMA MoE =================
// 64x64 tile, 4 waves each computing 32x32 via 2x2 mfma_f32_16x16x32_bf16, BK=64.
// LDS row stride 72 bf16 (144 B): conflict-free b128 frag reads + int4 staging writes.

#define MFMA_BF16 __builtin_amdgcn_mfma_f32_16x16x32_bf16

// up: Hb[e*PB+r][I] (bf16) = gelu(gather(X)[r] @ W1_e^T + b1_e)
__global__ __launch_bounds__(256) void k_moe_up_mfma(const float* __restrict__ X, int nTok,
                                                     const int* __restrict__ pairs, int PB,
                                                     const float* __restrict__ W1, const float* __restrict__ B1,
                                                     unsigned short* __restrict__ Hb) {
  int e = blockIdx.z;
  int n0 = blockIdx.x * 64, m0 = blockIdx.y * 64;
  __shared__ short As[64 * 72];
  __shared__ short Ws[64 * 72];
  __shared__ int rowIdx[64];
  int t = threadIdx.x;
  if (t < 64) {
    int r = m0 + t;
    int ri = (r < PB) ? pairs[(size_t)e * PB + r] : -1;
    if ((unsigned)ri >= (unsigned)nTok) ri = -1;
    rowIdx[t] = ri;
  }
  __syncthreads();
  int sr = t >> 2, sc = (t & 3) * 16;
  const float* Wrow = W1 + (size_t)e * I * H + (size_t)(n0 + sr) * H;
  int ri = rowIdx[sr];
  const float* Xrow = (ri >= 0) ? X + (size_t)ri * H : nullptr;
  int w = t >> 6, lane = t & 63;
  int wm = (w >> 1) * 32, wn = (w & 1) * 32;
  int frow = lane & 15, quad = lane >> 4;
  f32x4 acc[2][2] = {};
  for (int k0 = 0; k0 < H; k0 += 64) {
    // stage A (gathered fp32 -> bf16)
    {
      f32x4 f0 = {}, f1 = {}, f2 = {}, f3 = {};
      if (Xrow) {
        const f32x4* sp = (const f32x4*)(Xrow + k0 + sc);
        f0 = sp[0]; f1 = sp[1]; f2 = sp[2]; f3 = sp[3];
      }
      i32x4 lo, hi;
      lo.x = pack2(f0.x, f0.y); lo.y = pack2(f0.z, f0.w);
      lo.z = pack2(f1.x, f1.y); lo.w = pack2(f1.z, f1.w);
      hi.x = pack2(f2.x, f2.y); hi.y = pack2(f2.z, f2.w);
      hi.z = pack2(f3.x, f3.y); hi.w = pack2(f3.z, f3.w);
      *(i32x4*)(&As[sr * 72 + sc]) = lo;
      *(i32x4*)(&As[sr * 72 + sc + 8]) = hi;
    }
    // stage W (fp32 -> bf16)
    {
      const f32x4* sp = (const f32x4*)(Wrow + k0 + sc);
      f32x4 f0 = sp[0], f1 = sp[1], f2 = sp[2], f3 = sp[3];
      i32x4 lo, hi;
      lo.x = pack2(f0.x, f0.y); lo.y = pack2(f0.z, f0.w);
      lo.z = pack2(f1.x, f1.y); lo.w = pack2(f1.z, f1.w);
      hi.x = pack2(f2.x, f2.y); hi.y = pack2(f2.z, f2.w);
      hi.z = pack2(f3.x, f3.y); hi.w = pack2(f3.z, f3.w);
      *(i32x4*)(&Ws[sr * 72 + sc]) = lo;
      *(i32x4*)(&Ws[sr * 72 + sc + 8]) = hi;
    }
    __syncthreads();
#pragma unroll
    for (int ks = 0; ks < 64; ks += 32) {
      bf16x8 a0 = *(bf16x8*)(&As[(wm + frow) * 72 + ks + quad * 8]);
      bf16x8 a1 = *(bf16x8*)(&As[(wm + 16 + frow) * 72 + ks + quad * 8]);
      bf16x8 b0 = *(bf16x8*)(&Ws[(wn + frow) * 72 + ks + quad * 8]);
      bf16x8 b1 = *(bf16x8*)(&Ws[(wn + 16 + frow) * 72 + ks + quad * 8]);
      acc[0][0] = MFMA_BF16(a0, b0, acc[0][0], 0, 0, 0);
      acc[0][1] = MFMA_BF16(a0, b1, acc[0][1], 0, 0, 0);
      acc[1][0] = MFMA_BF16(a1, b0, acc[1][0], 0, 0, 0);
      acc[1][1] = MFMA_BF16(a1, b1, acc[1][1], 0, 0, 0);
    }
    __syncthreads();
  }
  const float* b1p = B1 + (size_t)e * I;
#pragma unroll
  for (int i = 0; i < 2; ++i) {
#pragma unroll
    for (int j = 0; j < 2; ++j) {
      int n = n0 + wn + j * 16 + frow;
      float bias = b1p[n];
#pragma unroll
      for (int reg = 0; reg < 4; ++reg) {
        int r = m0 + wm + i * 16 + quad * 4 + reg;
        if (r < PB) {
          float v = gelu_f(acc[i][j][reg] + bias);
          Hb[((size_t)e * PB + r) * I + n] = (unsigned short)f2bf_u(v);
        }
      }
    }
  }
}

// down: ACC[tok][H] += gather-scatter( Hb_e @ W2_e^T + b2_e )
__global__ __launch_bounds__(256) void k_moe_down_mfma(const unsigned short* __restrict__ Hb, int nTok,
                                                       const int* __restrict__ pairs, int PB,
                                                       const float* __restrict__ W2, const float* __restrict__ B2,
                                                       float* __restrict__ ACC) {
  int e = blockIdx.z;
  int n0 = blockIdx.x * 64, m0 = blockIdx.y * 64;
  __shared__ short As[64 * 72];
  __shared__ short Ws[64 * 72];
  __shared__ int tokLds[64];
  int t = threadIdx.x;
  if (t < 64) {
    int r = m0 + t;
    int tk = (r < PB) ? pairs[(size_t)e * PB + r] : 0;
    if ((unsigned)tk >= (unsigned)nTok) tk = 0;
    tokLds[t] = tk;
  }
  __syncthreads();
  int sr = t >> 2, sc = (t & 3) * 16;
  bool arow_ok = (m0 + sr) < PB;
  const unsigned short* Arow = Hb + ((size_t)e * PB + (m0 + sr)) * I;
  const float* Wrow = W2 + (size_t)e * H * I + (size_t)(n0 + sr) * I;
  int w = t >> 6, lane = t & 63;
  int wm = (w >> 1) * 32, wn = (w & 1) * 32;
  int frow = lane & 15, quad = lane >> 4;
  f32x4 acc[2][2] = {};
  for (int k0 = 0; k0 < I; k0 += 64) {
    // stage A (bf16 direct copy)
    {
      i32x4 lo = {}, hi = {};
      if (arow_ok) {
        const i32x4* sp = (const i32x4*)(Arow + k0 + sc);
        lo = sp[0]; hi = sp[1];
      }
      *(i32x4*)(&As[sr * 72 + sc]) = lo;
      *(i32x4*)(&As[sr * 72 + sc + 8]) = hi;
    }
    // stage W (fp32 -> bf16)
    {
      const f32x4* sp = (const f32x4*)(Wrow + k0 + sc);
      f32x4 f0 = sp[0], f1 = sp[1], f2 = sp[2], f3 = sp[3];
      i32x4 lo, hi;
      lo.x = pack2(f0.x, f0.y); lo.y = pack2(f0.z, f0.w);
      lo.z = pack2(f1.x, f1.y); lo.w = pack2(f1.z, f1.w);
      hi.x = pack2(f2.x, f2.y); hi.y = pack2(f2.z, f2.w);
      hi.z = pack2(f3.x, f3.y); hi.w = pack2(f3.z, f3.w);
      *(i32x4*)(&Ws[sr * 72 + sc]) = lo;
      *(i32x4*)(&Ws[sr * 72 + sc + 8]) = hi;
    }
    __syncthreads();
#pragma unroll
    for (int ks = 0; ks < 64; ks += 32) {
      bf16x8 a0 = *(bf16x8*)(&As[(wm + frow) * 72 + ks + quad * 8]);
      bf16x8 a1 = *(bf16x8*)(&As[(wm + 16 + frow) * 72 + ks + quad * 8]);
      bf16x8 b0 = *(bf16x8*)(&Ws[(wn + frow) * 72 + ks + quad * 8]);
      bf16x8 b1 = *(bf16x8*)(&Ws[(wn + 16 + frow) * 72 + ks + quad * 8]);
      acc[0][0] = MFMA_BF16(a0, b0, acc[0][0], 0, 0, 0);
      acc[0][1] = MFMA_BF16(a0, b1, acc[0][1], 0, 0, 0);
      acc[1][0] = MFMA_BF16(a1, b0, acc[1][0], 0, 0, 0);
      acc[1][1] = MFMA_BF16(a1, b1, acc[1][1], 0, 0, 0);
    }
    __syncthreads();
  }
  const float* b2p = B2 + (size_t)e * H;
#pragma unroll
  for (int i = 0; i < 2; ++i) {
#pragma unroll
    for (int j = 0; j < 2; ++j) {
      int n = n0 + wn + j * 16 + frow;
      float bias = b2p[n];
#pragma unroll
      for (int reg = 0; reg < 4; ++reg) {
        int r = m0 + wm + i * 16 + quad * 4 + reg;
        if (r < PB) {
          int tok = tokLds[wm + i * 16 + quad * 4 + reg];
          atomicAdd(&ACC[(size_t)tok * H + n], acc[i][j][reg] + bias);
        }
      }
    }
  }
}

// ---------------- final ----------------
__global__ __launch_bounds__(256) void k_final(const float* __restrict__ base, const float* __restrict__ acc,
                                               const int* __restrict__ cnt, float* __restrict__ out, int n) {
  int i = blockIdx.x * 256 + threadIdx.x;
  if (i >= n) return;
  int row = i >> 10;
  int c = cnt[row]; if (c < 1) c = 1;
  out[i] = base[i] + acc[i] / (float)c;
}

extern "C" void kernel_launch(void* const* d_in, const int* in_sizes, int n_in,
                              void* d_out, int out_size, void* d_ws, size_t ws_size,
                              hipStream_t stream) {
  float* out = (float*)d_out;
  dim3 blk(256);
  const int OUT_N = (int)(FQ + FIMG);
  int outN = out_size;

  static const int EXP[25] = {
    B * T * H, B * V * H, B * L * H,
    3 * H * H, 3 * H, H * H, H,
    3 * H * H, 3 * H, H * H, H,
    E * 2 * H, E, E * 2 * H, E,
    E * I * H, E * I, E * H * I, E * H,
    H, H, H, H, H, H
  };
  if (n_in != 25) { k_diag<<<dim3((outN + 255) / 256), blk, 0, stream>>>(out, outN, 40000.f); return; }
  for (int i = 0; i < 25; ++i)
    if (in_sizes[i] != EXP[i]) {
      k_diag<<<dim3((outN + 255) / 256), blk, 0, stream>>>(out, outN, 20000.f + 1000.f * i);
      return;
    }
  if (out_size != OUT_N) { k_diag<<<dim3((outN + 255) / 256), blk, 0, stream>>>(out, outN, 30000.f); return; }
  if (ws_size < WS_FLOATS * sizeof(float)) {
    k_diag<<<dim3((outN + 255) / 256), blk, 0, stream>>>(out, outN, 12345.f);
    return;
  }

  float* wsf = (float*)d_ws;
  float* Q = wsf + oQ;  float* XN = wsf + oXN;  float* AO = wsf + oAO;  float* IMG32 = wsf + oIMG;
  float* CTXI = wsf + oCTXI;  float* CTXT = wsf + oCTXT;
  float* PRT = wsf + oPRT;    float* PRI = wsf + oPRI;
  float* SW = wsf + oSW;
  int* FLAG = (int*)(wsf + oINT);
  int* PAIRS_T = FLAG + 1;
  int* PAIRS_I = PAIRS_T + E * PBT;
  int* CNT_T = PAIRS_I + E * PBI;
  int* CNT_I = CNT_T + B * T;
  float* QKV = wsf + oBIG;                       // attention phase
  unsigned short* HBu = (unsigned short*)(wsf + oBIG);  // MoE phase (QKV dead)

  k_detect<<<dim3(1), blk, 0, stream>>>(d_in[0], FLAG);

  struct CV { int idx; size_t off; int n; };
  const CV cvs[16] = {
    {4, sSA_B_IN, 3 * H}, {6, sSA_B_OUT, H}, {8, sCA_B_IN, 3 * H}, {10, sCA_B_OUT, H},
    {11, sGIW, E * 2 * H}, {12, sGIB, E}, {13, sGTW, E * 2 * H}, {14, sGTB, E},
    {16, sEB1, E * I}, {18, sEB2, E * H},
    {19, sLNQG, H}, {20, sLNQB, H}, {21, sLNCG, H}, {22, sLNCB, H}, {23, sLNFG, H}, {24, sLNFB, H}
  };
  for (int c = 0; c < 16; ++c)
    k_cvt2<<<dim3((cvs[c].n + 255) / 256), blk, 0, stream>>>(d_in[cvs[c].idx], SW + cvs[c].off, cvs[c].n, FLAG);

  k_cvt2<<<dim3((int)(FQ / 256)), blk, 0, stream>>>(d_in[0], Q, (int)FQ, FLAG);
  k_cvt2<<<dim3((int)(FIMG / 256)), blk, 0, stream>>>(d_in[1], IMG32, (int)FIMG, FLAG);

  // ---- 1) self-attention ----
  k_ln<<<dim3(B * T), blk, 0, stream>>>(Q, SW + sLNQG, SW + sLNQB, XN);
  k_gemm<false><<<dim3(3 * H / 64, B * T / 64), blk, 0, stream>>>(
      XN, H, d_in[3], 0, H, SW + sSA_B_IN, QKV, 3 * H, B * T, 3 * H, H, FLAG);
  k_attn<<<dim3(T / 4, NH, B), blk, 0, stream>>>(QKV, 3 * H, QKV + H, 3 * H, QKV + 2 * H, 3 * H, AO, T, T);
  k_gemm<true><<<dim3(H / 64, B * T / 64), blk, 0, stream>>>(
      AO, H, d_in[5], 0, H, SW + sSA_B_OUT, Q, H, B * T, H, H, FLAG);

  // ---- 2) cross-attention ----
  k_ln<<<dim3(B * T), blk, 0, stream>>>(Q, SW + sLNCG, SW + sLNCB, XN);
  k_gemm<false><<<dim3(H / 64, B * T / 64), blk, 0, stream>>>(
      XN, H, d_in[7], 0, H, SW + sCA_B_IN, QKV, H, B * T, H, H, FLAG);
  k_gemm<false><<<dim3(2 * H / 64, B * V / 64), blk, 0, stream>>>(
      IMG32, H, d_in[7], (size_t)H * H, H, SW + sCA_B_IN + H, QKV + FQ, 2 * H, B * V, 2 * H, H, FLAG);
  k_attn<<<dim3(T / 4, NH, B), blk, 0, stream>>>(QKV, H, QKV + FQ, 2 * H, QKV + FQ + H, 2 * H, AO, T, V);
  k_gemm<true><<<dim3(H / 64, B * T / 64), blk, 0, stream>>>(
      AO, H, d_in[9], 0, H, SW + sCA_B_OUT, Q, H, B * T, H, H, FLAG);

  // ---- 3) gating ----
  k_mean_f32<<<dim3((B * H) / 256), blk, 0, stream>>>(IMG32, CTXI, V);
  k_mean_in<<<dim3((B * H) / 256), blk, 0, stream>>>(d_in[2], CTXT, L, FLAG);
  k_gate<<<dim3(B * T), blk, 0, stream>>>(Q, CTXI, SW + sGTW, SW + sGTB, PRT, T);
  k_gate<<<dim3(B * V), blk, 0, stream>>>(IMG32, CTXT, SW + sGIW, SW + sGIB, PRI, V);
  k_zeroi<<<dim3((B * T + B * V + 255) / 256), blk, 0, stream>>>(CNT_T, B * T + B * V);

  // ---- 4) text MoE (MFMA) ----
  k_topk<<<dim3(E, B), blk, 0, stream>>>(PRT, T, KT, PAIRS_T, CNT_T, PBT);
  k_ln<<<dim3(B * T), blk, 0, stream>>>(Q, SW + sLNFG, SW + sLNFB, XN);
  k_zerof<<<dim3((int)(FQ / 256)), blk, 0, stream>>>(AO, (int)FQ);
  k_moe_up_mfma<<<dim3(I / 64, PBT / 64, E), blk, 0, stream>>>(
      XN, B * T, PAIRS_T, PBT, (const float*)d_in[15], (const float*)d_in[16], HBu);
  k_moe_down_mfma<<<dim3(H / 64, PBT / 64, E), blk, 0, stream>>>(
      HBu, B * T, PAIRS_T, PBT, (const float*)d_in[17], (const float*)d_in[18], AO);
  k_final<<<dim3((int)(FQ / 256)), blk, 0, stream>>>(Q, AO, CNT_T, out, (int)FQ);

  // ---- 5) image MoE (MFMA) ----
  k_topk<<<dim3(E, B), blk, 0, stream>>>(PRI, V, KI, PAIRS_I, CNT_I, PBI);
  k_zerof<<<dim3((int)(FIMG / 256)), blk, 0, stream>>>(AO, (int)FIMG);
  k_moe_up_mfma<<<dim3(I / 64, (PBI + 63) / 64, E), blk, 0, stream>>>(
      IMG32, B * V, PAIRS_I, PBI, (const float*)d_in[15], (const float*)d_in[16], HBu);
  k_moe_down_mfma<<<dim3(H / 64, (PBI + 63) / 64, E), blk, 0, stream>>>(
      HBu, B * V, PAIRS_I, PBI, (const float*)d_in[17], (const float*)d_in[18], AO);
  k_final<<<dim3((int)(FIMG / 256)), blk, 0, stream>>>(IMG32, AO, CNT_I, out + FQ, (int)FIMG);
}